// Round 4
// baseline (225.626 us; speedup 1.0000x reference)
//
#include <hip/hip_runtime.h>

// Reference: out = x @ eye(4096) == x. Pure float32 copy, memory-bound.
// 33,554,432 floats = 134.2 MB in + 134.2 MB out -> ~42.7 us at 6.29 TB/s.
//
// Round-3 A/B history:
//   R0 baseline 1-float4/thread kernel: 217.5 us total
//   R1 4x unroll + nt stores:           228.4 us (regressed)
//   R2 4x unroll, plain stores:         225.5 us (still worse; unroll dead)
// The timed region contains ~160 us of harness poison-fills (2 x ~80 us
// fillBufferAligned @ 6.7-6.85 TB/s) that we cannot control; the copy is the
// remaining ~60 us vs ~43 us ideal.
//
// This round: stop hand-rolling. Use the runtime's tuned D2D copy path
// (hipMemcpyAsync, graph-capture-legal: it records as a memcpy node). The
// fills prove the chip sustains ~6.8 TB/s on simple streams; AMD's blit/SDMA
// copy is the best-tuned mixed read+write stream available.

extern "C" void kernel_launch(void* const* d_in, const int* in_sizes, int n_in,
                              void* d_out, int out_size, void* d_ws, size_t ws_size,
                              hipStream_t stream) {
    const void* x = d_in[0];
    // out_size is the output byte count? It is used as out_size/4 = n4
    // (float4 count) historically with out_size in FLOATS: 33,554,432 floats.
    // Copy bytes = floats * 4.
    size_t bytes = (size_t)out_size * 4;  // 134,217,728 bytes
    hipMemcpyAsync(d_out, x, bytes, hipMemcpyDeviceToDevice, stream);
}

// Round 5
// 218.601 us; speedup vs baseline: 1.0321x; 1.0321x over previous
//
#include <hip/hip_runtime.h>

// Reference: out = x @ eye(4096) == x. Pure float32 copy, memory-bound.
// 8192*4096 floats = 33,554,432 elements = 8,388,608 float4s.
// Traffic: 134.2 MB read + 134.2 MB write = 268.4 MB -> ~42.7 us at 6.29 TB/s.
//
// FINAL (revert to best): mechanism sweep across 4 rounds —
//   R0 1-float4/thread kernel:  217.5 us  <- best
//   R1 4x unroll + nt stores:   228.4 us
//   R2 4x unroll, plain stores: 225.5 us
//   R3 hipMemcpyAsync (blit):   225.6 us
// Timed region = ~158 us of harness poison-fills (2 x ~79 us @ ~6.8 TB/s,
// uncontrollable) + copy (~43 us ideal) + ~12-15 us dispatch gaps. The simple
// max-TLP copy (32768 blocks, 1 float4/lane) is already at the ~6.3 TB/s
// mixed read+write ceiling (learn_hip m13); deeper per-lane MLP, nt stores,
// and the runtime blit all measured neutral-to-worse.

__global__ __launch_bounds__(256) void copy_f4(const float4* __restrict__ in,
                                               float4* __restrict__ out,
                                               int n4) {
    int i = blockIdx.x * blockDim.x + threadIdx.x;
    if (i < n4) {
        out[i] = in[i];
    }
}

extern "C" void kernel_launch(void* const* d_in, const int* in_sizes, int n_in,
                              void* d_out, int out_size, void* d_ws, size_t ws_size,
                              hipStream_t stream) {
    const float4* x = (const float4*)d_in[0];
    float4* out = (float4*)d_out;
    int n4 = out_size / 4;  // 33,554,432 / 4 = 8,388,608
    int block = 256;
    int grid = (n4 + block - 1) / block;  // 32768 blocks
    copy_f4<<<grid, block, 0, stream>>>(x, out, n4);
}